// Round 6
// baseline (685.405 us; speedup 1.0000x reference)
//
#include <hip/hip_runtime.h>
#include <hip/hip_bf16.h>
#include <cstdint>

#define D_MODEL 1024
#define NHEAD 16
#define DKH 64
#define BATCH 4
#define SEQ 2048
#define M_TOT (BATCH*SEQ)   // 8192

typedef __bf16 bf16;
typedef __bf16 bf16x8 __attribute__((ext_vector_type(8)));
typedef __bf16 bf16x4 __attribute__((ext_vector_type(4)));
typedef float  f32x4  __attribute__((ext_vector_type(4)));

// async global->LDS, 16B per lane. LDS dest must be wave-uniform base; HW adds lane*16.
__device__ __forceinline__ void async_ld16(const void* g, void* l) {
    __builtin_amdgcn_global_load_lds(
        (__attribute__((address_space(1))) void*)(uintptr_t)g,
        (__attribute__((address_space(3))) void*)(uintptr_t)l,
        16, 0, 0);
}

// ---------------- merged convert: x fp32->bf16 (blocks 0..8191) and
// weight convert+transpose W[K][N] fp32 -> Wt[N][K] bf16 (blocks 8192..12287) ----------------
__global__ __launch_bounds__(256) void k_cvt(const float* __restrict__ x,
                                             bf16* __restrict__ xb,
                                             const float* __restrict__ wq,
                                             const float* __restrict__ wk,
                                             const float* __restrict__ wv,
                                             const float* __restrict__ wo,
                                             bf16* __restrict__ wt) {
    __shared__ float t[32][33];
    int bid = blockIdx.x;
    if (bid < 8192) {
        int i = (bid * 256 + threadIdx.x) * 4;
        float4 f = *(const float4*)(x + i);
        bf16x4 o;
        o[0] = (bf16)f.x; o[1] = (bf16)f.y; o[2] = (bf16)f.z; o[3] = (bf16)f.w;
        *(bf16x4*)(xb + i) = o;
    } else {
        int wb = bid - 8192;                  // 0..4095
        int z = wb >> 10;
        int rem = wb & 1023;
        const float* W = (z == 0) ? wq : (z == 1) ? wk : (z == 2) ? wv : wo;
        bf16* T = wt + (size_t)z * D_MODEL * D_MODEL;
        int tx = threadIdx.x & 31, ty = threadIdx.x >> 5;   // (32,8)
        int bx = (rem & 31) * 32, by = (rem >> 5) * 32;
#pragma unroll
        for (int i = 0; i < 4; i++)
            t[ty + i * 8][tx] = W[(size_t)(by + ty + i * 8) * D_MODEL + bx + tx];
        __syncthreads();
#pragma unroll
        for (int i = 0; i < 4; i++)
            T[(size_t)(bx + ty + i * 8) * D_MODEL + by + tx] = (bf16)t[tx][ty + i * 8];
    }
}

// ---------------- fused QKV GEMM, z-merged + XCD-swizzled + BK=64 ----------------
// Grid (64 m-tiles, 24 n-tiles over 3072 cols). id = bx + 64*by -> id%8 = bx%8:
// all n-tiles of one m-tile run on the SAME XCD -> A-tile HBM-fetched once.
// BK=64 via two chunked [128][32] LDS panels; fragments loaded 32-wide per
// sub-chunk so VGPR stays <=128 (launch_bounds(256,4)). Barriers halved.
// z = n0>>10: z<2 -> transposed-MFMA epilogue into qkv [B,H,S,Dk] (Q scaled);
// z=2 -> normal epilogue writes V^T directly into vtg [bh][Dk][S].
__global__ __launch_bounds__(256, 4) void k_gemm_qkv(const bf16* __restrict__ xb,
                                                     const bf16* __restrict__ wt,
                                                     const float* __restrict__ bq,
                                                     const float* __restrict__ bk,
                                                     const float* __restrict__ bv,
                                                     bf16* __restrict__ qkv,
                                                     bf16* __restrict__ vtg) {
    __shared__ bf16 As[2 * 128 * 32];   // 16 KB: two 32-wide k-panels
    __shared__ bf16 Bs[2 * 128 * 32];   // 16 KB

    int tid = threadIdx.x;
    int lane = tid & 63, wid = tid >> 6;
    int ln = lane & 15, qd = lane >> 4;
    int wm = wid >> 1, wn = wid & 1;
    int m0 = blockIdx.x * 128;                 // m-tile (x-fastest -> XCD pin)
    int n0 = blockIdx.y * 128;                 // global col in [0,3072)
    int z = n0 >> 10;
    const float* bias = (z == 0) ? bq : (z == 1) ? bk : bv;
    float scale = (z == 0) ? 0.125f * 1.44269504088896f : 1.0f;  // 1/sqrt(Dk)*log2e folded into Q
    bool swapped = (z < 2);

    f32x4 zero4 = {0.f, 0.f, 0.f, 0.f};
    f32x4 acc[4][4];
#pragma unroll
    for (int i = 0; i < 4; i++)
#pragma unroll
        for (int j = 0; j < 4; j++) acc[i][j] = zero4;

    for (int k0 = 0; k0 < D_MODEL; k0 += 64) {
#pragma unroll
        for (int t = 0; t < 4; t++) {
            int c = t * 256 + tid;             // 0..1023, 16B each
            int ch = c >> 9, w = c & 511;      // panel, slot
            int row = w >> 2, part = w & 3;
            async_ld16(xb + (size_t)(m0 + row) * D_MODEL + k0 + ch * 32 + part * 8,
                       As + ch * 4096 + (w & ~63) * 8);
            async_ld16(wt + (size_t)(n0 + row) * D_MODEL + k0 + ch * 32 + part * 8,
                       Bs + ch * 4096 + (w & ~63) * 8);
        }
        __syncthreads();
#pragma unroll
        for (int kc = 0; kc < 2; kc++) {
            bf16x8 af[4], bfr[4];
#pragma unroll
            for (int mi = 0; mi < 4; mi++)
                af[mi] = *(const bf16x8*)(As + kc * 4096 + (wm * 64 + mi * 16 + ln) * 32 + qd * 8);
#pragma unroll
            for (int ni = 0; ni < 4; ni++)
                bfr[ni] = *(const bf16x8*)(Bs + kc * 4096 + (wn * 64 + ni * 16 + ln) * 32 + qd * 8);
            if (swapped) {
#pragma unroll
                for (int mi = 0; mi < 4; mi++)
#pragma unroll
                    for (int ni = 0; ni < 4; ni++)
                        acc[mi][ni] = __builtin_amdgcn_mfma_f32_16x16x32_bf16(bfr[ni], af[mi],
                                                                              acc[mi][ni], 0, 0, 0);
            } else {
#pragma unroll
                for (int mi = 0; mi < 4; mi++)
#pragma unroll
                    for (int ni = 0; ni < 4; ni++)
                        acc[mi][ni] = __builtin_amdgcn_mfma_f32_16x16x32_bf16(af[mi], bfr[ni],
                                                                              acc[mi][ni], 0, 0, 0);
            }
        }
        __syncthreads();
    }

    if (swapped) {
        // D[n][m]: lane holds x-row s (fixed), 4 consecutive W-cols (d)
        bf16* out = qkv + (size_t)z * M_TOT * D_MODEL;
#pragma unroll
        for (int mi = 0; mi < 4; mi++) {
            int srow = m0 + wm * 64 + mi * 16 + ln;
            int b = srow >> 11, s = srow & 2047;
#pragma unroll
            for (int ni = 0; ni < 4; ni++) {
                int colz = (n0 & 1023) + wn * 64 + ni * 16 + qd * 4;
                f32x4 bb = *(const f32x4*)(bias + colz);
                int h = colz >> 6, d = colz & 63;
                bf16x4 p;
#pragma unroll
                for (int r = 0; r < 4; r++)
                    p[r] = (bf16)((acc[mi][ni][r] + bb[r]) * scale);
                *(bf16x4*)(out + (((size_t)(b * NHEAD + h)) * SEQ + s) * DKH + d) = p;
            }
        }
    } else {
        // D[m][n]: lane holds W-col d (fixed), 4 consecutive x-rows (s) -> V^T direct
#pragma unroll
        for (int ni = 0; ni < 4; ni++) {
            int colz = (n0 & 1023) + wn * 64 + ni * 16 + ln;
            float bcol = bias[colz];
            int h = colz >> 6, d = colz & 63;
#pragma unroll
            for (int mi = 0; mi < 4; mi++) {
                int rb = m0 + wm * 64 + mi * 16 + qd * 4;
                int b = rb >> 11, s = rb & 2047;
                bf16x4 p;
#pragma unroll
                for (int r = 0; r < 4; r++)
                    p[r] = (bf16)(acc[mi][ni][r] + bcol);
                *(bf16x4*)(vtg + (((size_t)(b * NHEAD + h)) * DKH + d) * SEQ + s) = p;
            }
        }
    }
}

// ---------------- flash attention v4: transposed-score trick ----------------
#define PROW 40
__global__ __launch_bounds__(256, 4) void k_attn(const bf16* __restrict__ qg,
                                                 const bf16* __restrict__ kg,
                                                 const bf16* __restrict__ vtg,
                                                 bf16* __restrict__ og) {
    __shared__ bf16 Ks[2 * 64 * 32];        // 8 KB
    __shared__ bf16 Vs[2 * 64 * 32];        // 8 KB
    __shared__ bf16 Ps[4 * 2 * 32 * PROW];  // 20 KB

    int tid = threadIdx.x;
    int lane = tid & 63, wid = tid >> 6;
    int ln = lane & 15, qd = lane >> 4;
    int bh = blockIdx.y;
    int q0 = blockIdx.x * 128;
    int b = bh >> 4, h = bh & 15;

    const bf16* qp = qg + (size_t)bh * SEQ * DKH;
    const bf16* kp = kg + (size_t)bh * SEQ * DKH;
    const bf16* vp = vtg + (size_t)bh * DKH * SEQ;

    // Q fragments (pre-scaled by log2e/8), used as B operand of swapped score MFMA
    bf16x8 qa[2][2];
#pragma unroll
    for (int mi = 0; mi < 2; mi++)
#pragma unroll
        for (int kc = 0; kc < 2; kc++)
            qa[mi][kc] = *(const bf16x8*)(qp + (size_t)(q0 + wid * 32 + mi * 16 + ln) * DKH
                                          + kc * 32 + qd * 8);

    // ones B-fragment: B[k][0]=1 for all k -> lanes with ln==0 hold 1.0
    bf16 onev = (bf16)((ln == 0) ? 1.0f : 0.0f);
    bf16x8 ones_frag = {onev, onev, onev, onev, onev, onev, onev, onev};

    f32x4 zero4 = {0.f, 0.f, 0.f, 0.f};
    f32x4 o_acc[2][4];
    f32x4 l_acc[2];
#pragma unroll
    for (int mi = 0; mi < 2; mi++) {
        l_acc[mi] = zero4;
#pragma unroll
        for (int nd = 0; nd < 4; nd++) o_acc[mi][nd] = zero4;
    }

    bf16* Pw = Ps + wid * 2 * 32 * PROW;

    for (int kt = 0; kt < SEQ; kt += 64) {
        // stage K tile -> Ks[2][64][32] and Vt tile -> Vs[2][64][32] (chunked, 64B rows)
#pragma unroll
        for (int t = 0; t < 2; t++) {
            int c = t * 256 + tid;                 // 0..511, 16B each
            int ch = c >> 8, w = c & 255;
            int row = w >> 2, part = w & 3;
            async_ld16(kp + (size_t)(kt + row) * DKH + ch * 32 + part * 8,
                       Ks + (c & ~63) * 8);
            async_ld16(vp + (size_t)row * SEQ + kt + ch * 32 + part * 8,
                       Vs + (c & ~63) * 8);
        }
        __syncthreads();

        // S^T = K Q^T (log2 domain): A=K-frag, B=Q-frag; row=key qd*4+r, col=q=ln
        f32x4 sc[2][4];
#pragma unroll
        for (int mi = 0; mi < 2; mi++)
#pragma unroll
            for (int ni = 0; ni < 4; ni++) sc[mi][ni] = zero4;
#pragma unroll
        for (int kc = 0; kc < 2; kc++) {
#pragma unroll
            for (int ni = 0; ni < 4; ni++) {
                bf16x8 kb = *(const bf16x8*)(Ks + kc * 2048 + (ni * 16 + ln) * 32 + qd * 8);
#pragma unroll
                for (int mi = 0; mi < 2; mi++)
                    sc[mi][ni] = __builtin_amdgcn_mfma_f32_16x16x32_bf16(kb, qa[mi][kc],
                                                                         sc[mi][ni], 0, 0, 0);
            }
        }

        // P = exp2(S): lane owns 4 consecutive keys of P-row q=mi*16+ln -> b64 write
#pragma unroll
        for (int mi = 0; mi < 2; mi++) {
#pragma unroll
            for (int ni = 0; ni < 4; ni++) {
                bf16x4 p4;
#pragma unroll
                for (int r = 0; r < 4; r++)
                    p4[r] = (bf16)__builtin_amdgcn_exp2f(sc[mi][ni][r]);
                *(bf16x4*)(Pw + (ni >> 1) * 32 * PROW + (mi * 16 + ln) * PROW
                           + (ni & 1) * 16 + qd * 4) = p4;
            }
        }

        // O += P V ; l += P * ones  (A=P from LDS round-trip)
#pragma unroll
        for (int kc2 = 0; kc2 < 2; kc2++) {
            bf16x8 pf[2];
#pragma unroll
            for (int mi = 0; mi < 2; mi++) {
                pf[mi] = *(const bf16x8*)(Pw + kc2 * 32 * PROW + (mi * 16 + ln) * PROW + qd * 8);
                l_acc[mi] = __builtin_amdgcn_mfma_f32_16x16x32_bf16(pf[mi], ones_frag,
                                                                    l_acc[mi], 0, 0, 0);
            }
#pragma unroll
            for (int nd = 0; nd < 4; nd++) {
                bf16x8 vf = *(const bf16x8*)(Vs + kc2 * 2048 + (nd * 16 + ln) * 32 + qd * 8);
#pragma unroll
                for (int mi = 0; mi < 2; mi++)
                    o_acc[mi][nd] = __builtin_amdgcn_mfma_f32_16x16x32_bf16(pf[mi], vf,
                                                                            o_acc[mi][nd], 0, 0, 0);
            }
        }
        __syncthreads();
    }

    // normalize and store O as bf16 [B,S,H*Dk]; row-sum lives in col 0 (lanes ln==0)
#pragma unroll
    for (int mi = 0; mi < 2; mi++) {
#pragma unroll
        for (int r = 0; r < 4; r++) {
            float lsum = __shfl(l_acc[mi][r], lane & 48, 64);  // broadcast from ln==0 of this qd
            float inv = 1.0f / lsum;
            int s = q0 + wid * 32 + mi * 16 + qd * 4 + r;
            size_t rowoff = ((size_t)b * SEQ + s) * D_MODEL + h * DKH;
#pragma unroll
            for (int nd = 0; nd < 4; nd++)
                og[rowoff + nd * 16 + ln] = (bf16)(o_acc[mi][nd][r] * inv);
        }
    }
}

// ---------------- output GEMM: O[8192x1024] @ Wo + bo -> fp32 ----------------
// Same BK=64 + XCD-swizzled grid (x=m, y=n). Transposed epilogue, float4 stores.
__global__ __launch_bounds__(256, 4) void k_gemm_out(const bf16* __restrict__ ob,
                                                     const bf16* __restrict__ wot,
                                                     const float* __restrict__ bo,
                                                     float* __restrict__ out) {
    __shared__ bf16 As[2 * 128 * 32];
    __shared__ bf16 Bs[2 * 128 * 32];

    int tid = threadIdx.x;
    int lane = tid & 63, wid = tid >> 6;
    int ln = lane & 15, qd = lane >> 4;
    int wm = wid >> 1, wn = wid & 1;
    int m0 = blockIdx.x * 128, n0 = blockIdx.y * 128;

    f32x4 zero4 = {0.f, 0.f, 0.f, 0.f};
    f32x4 acc[4][4];
#pragma unroll
    for (int i = 0; i < 4; i++)
#pragma unroll
        for (int j = 0; j < 4; j++) acc[i][j] = zero4;

    for (int k0 = 0; k0 < D_MODEL; k0 += 64) {
#pragma unroll
        for (int t = 0; t < 4; t++) {
            int c = t * 256 + tid;
            int ch = c >> 9, w = c & 511;
            int row = w >> 2, part = w & 3;
            async_ld16(ob + (size_t)(m0 + row) * D_MODEL + k0 + ch * 32 + part * 8,
                       As + ch * 4096 + (w & ~63) * 8);
            async_ld16(wot + (size_t)(n0 + row) * D_MODEL + k0 + ch * 32 + part * 8,
                       Bs + ch * 4096 + (w & ~63) * 8);
        }
        __syncthreads();
#pragma unroll
        for (int kc = 0; kc < 2; kc++) {
            bf16x8 af[4], bfr[4];
#pragma unroll
            for (int mi = 0; mi < 4; mi++)
                af[mi] = *(const bf16x8*)(As + kc * 4096 + (wm * 64 + mi * 16 + ln) * 32 + qd * 8);
#pragma unroll
            for (int ni = 0; ni < 4; ni++)
                bfr[ni] = *(const bf16x8*)(Bs + kc * 4096 + (wn * 64 + ni * 16 + ln) * 32 + qd * 8);
#pragma unroll
            for (int mi = 0; mi < 4; mi++)
#pragma unroll
                for (int ni = 0; ni < 4; ni++)
                    acc[mi][ni] = __builtin_amdgcn_mfma_f32_16x16x32_bf16(bfr[ni], af[mi],
                                                                          acc[mi][ni], 0, 0, 0);
        }
        __syncthreads();
    }

#pragma unroll
    for (int mi = 0; mi < 4; mi++) {
        int row = m0 + wm * 64 + mi * 16 + ln;
#pragma unroll
        for (int ni = 0; ni < 4; ni++) {
            int col4 = n0 + wn * 64 + ni * 16 + qd * 4;
            f32x4 bb = *(const f32x4*)(bo + col4);
            f32x4 v;
#pragma unroll
            for (int r = 0; r < 4; r++) v[r] = acc[mi][ni][r] + bb[r];
            *(f32x4*)(out + (size_t)row * D_MODEL + col4) = v;
        }
    }
}

extern "C" void kernel_launch(void* const* d_in, const int* in_sizes, int n_in,
                              void* d_out, int out_size, void* d_ws, size_t ws_size,
                              hipStream_t stream) {
    const float* x  = (const float*)d_in[0];
    const float* wq = (const float*)d_in[1];
    const float* bq = (const float*)d_in[2];
    const float* wk = (const float*)d_in[3];
    const float* bk = (const float*)d_in[4];
    const float* wv = (const float*)d_in[5];
    const float* bv = (const float*)d_in[6];
    const float* wo = (const float*)d_in[7];
    const float* bo = (const float*)d_in[8];
    float* out = (float*)d_out;

    char* ws = (char*)d_ws;
    bf16* xb  = (bf16*)ws;                    // 16.8 MB (reused as og after QKV GEMM)
    bf16* wt  = (bf16*)(ws + 16777216);       //  8.4 MB (wq,wk,wv,wo transposed, contiguous)
    bf16* qkv = (bf16*)(ws + 25165824);       // Q,K
    bf16* vtg = (bf16*)(ws + 75497472);       // V^T written directly by GEMM
    bf16* og  = xb;

    k_cvt<<<dim3(8192 + 4096), dim3(256), 0, stream>>>(x, xb, wq, wk, wv, wo, wt);
    k_gemm_qkv<<<dim3(64, 24), dim3(256), 0, stream>>>(xb, wt, bq, bk, bv, qkv, vtg);
    k_attn<<<dim3(16, 64), dim3(256), 0, stream>>>(qkv, qkv + (size_t)M_TOT * D_MODEL, vtg, og);
    k_gemm_out<<<dim3(64, 8), dim3(256), 0, stream>>>(og, wt + 3 * (size_t)D_MODEL * D_MODEL,
                                                      bo, out);
}

// Round 7
// 280.210 us; speedup vs baseline: 2.4460x; 2.4460x over previous
//
#include <hip/hip_runtime.h>
#include <hip/hip_bf16.h>
#include <cstdint>

#define D_MODEL 1024
#define NHEAD 16
#define DKH 64
#define BATCH 4
#define SEQ 2048
#define M_TOT (BATCH*SEQ)   // 8192

typedef __bf16 bf16;
typedef __bf16 bf16x8 __attribute__((ext_vector_type(8)));
typedef __bf16 bf16x4 __attribute__((ext_vector_type(4)));
typedef float  f32x4  __attribute__((ext_vector_type(4)));

// async global->LDS, 16B per lane. LDS dest must be wave-uniform base; HW adds lane*16.
__device__ __forceinline__ void async_ld16(const void* g, void* l) {
    __builtin_amdgcn_global_load_lds(
        (__attribute__((address_space(1))) void*)(uintptr_t)g,
        (__attribute__((address_space(3))) void*)(uintptr_t)l,
        16, 0, 0);
}

// ---------------- merged convert: x fp32->bf16 (blocks 0..8191) and
// weight convert+transpose W[K][N] fp32 -> Wt[N][K] bf16 (blocks 8192..12287) ----------------
__global__ __launch_bounds__(256) void k_cvt(const float* __restrict__ x,
                                             bf16* __restrict__ xb,
                                             const float* __restrict__ wq,
                                             const float* __restrict__ wk,
                                             const float* __restrict__ wv,
                                             const float* __restrict__ wo,
                                             bf16* __restrict__ wt) {
    __shared__ float t[32][33];
    int bid = blockIdx.x;
    if (bid < 8192) {
        int i = (bid * 256 + threadIdx.x) * 4;
        float4 f = *(const float4*)(x + i);
        bf16x4 o;
        o[0] = (bf16)f.x; o[1] = (bf16)f.y; o[2] = (bf16)f.z; o[3] = (bf16)f.w;
        *(bf16x4*)(xb + i) = o;
    } else {
        int wb = bid - 8192;                  // 0..4095
        int z = wb >> 10;
        int rem = wb & 1023;
        const float* W = (z == 0) ? wq : (z == 1) ? wk : (z == 2) ? wv : wo;
        bf16* T = wt + (size_t)z * D_MODEL * D_MODEL;
        int tx = threadIdx.x & 31, ty = threadIdx.x >> 5;   // (32,8)
        int bx = (rem & 31) * 32, by = (rem >> 5) * 32;
#pragma unroll
        for (int i = 0; i < 4; i++)
            t[ty + i * 8][tx] = W[(size_t)(by + ty + i * 8) * D_MODEL + bx + tx];
        __syncthreads();
#pragma unroll
        for (int i = 0; i < 4; i++)
            T[(size_t)(bx + ty + i * 8) * D_MODEL + by + tx] = (bf16)t[tx][ty + i * 8];
    }
}

// ---------------- fused QKV GEMM, z-merged + XCD-swizzled + BK=64 ----------------
// Grid (64 m-tiles, 24 n-tiles over 3072 cols). id = bx + 64*by -> id%8 = bx%8:
// all n-tiles of one m-tile run on the SAME XCD -> A-tile HBM-fetched once.
// NOTE R6 lesson: NO min-waves launch bound here — forcing 4 waves/SIMD on a
// ~120-VGPR kernel spilled acc to scratch (WRITE_SIZE 49MB->1.4GB, 5x slower).
// Plain bounds give VGPR=120 -> 4 waves/SIMD naturally.
__global__ __launch_bounds__(256) void k_gemm_qkv(const bf16* __restrict__ xb,
                                                  const bf16* __restrict__ wt,
                                                  const float* __restrict__ bq,
                                                  const float* __restrict__ bk,
                                                  const float* __restrict__ bv,
                                                  bf16* __restrict__ qkv,
                                                  bf16* __restrict__ vtg) {
    __shared__ bf16 As[2 * 128 * 32];   // 16 KB: two 32-wide k-panels
    __shared__ bf16 Bs[2 * 128 * 32];   // 16 KB

    int tid = threadIdx.x;
    int lane = tid & 63, wid = tid >> 6;
    int ln = lane & 15, qd = lane >> 4;
    int wm = wid >> 1, wn = wid & 1;
    int m0 = blockIdx.x * 128;                 // m-tile (x-fastest -> XCD pin)
    int n0 = blockIdx.y * 128;                 // global col in [0,3072)
    int z = n0 >> 10;
    const float* bias = (z == 0) ? bq : (z == 1) ? bk : bv;
    float scale = (z == 0) ? 0.125f * 1.44269504088896f : 1.0f;  // 1/sqrt(Dk)*log2e folded into Q
    bool swapped = (z < 2);

    f32x4 zero4 = {0.f, 0.f, 0.f, 0.f};
    f32x4 acc[4][4];
#pragma unroll
    for (int i = 0; i < 4; i++)
#pragma unroll
        for (int j = 0; j < 4; j++) acc[i][j] = zero4;

    for (int k0 = 0; k0 < D_MODEL; k0 += 64) {
#pragma unroll
        for (int t = 0; t < 4; t++) {
            int c = t * 256 + tid;             // 0..1023, 16B each
            int ch = c >> 9, w = c & 511;      // panel, slot
            int row = w >> 2, part = w & 3;
            async_ld16(xb + (size_t)(m0 + row) * D_MODEL + k0 + ch * 32 + part * 8,
                       As + ch * 4096 + (w & ~63) * 8);
            async_ld16(wt + (size_t)(n0 + row) * D_MODEL + k0 + ch * 32 + part * 8,
                       Bs + ch * 4096 + (w & ~63) * 8);
        }
        __syncthreads();
#pragma unroll
        for (int kc = 0; kc < 2; kc++) {
            bf16x8 af[4], bfr[4];
#pragma unroll
            for (int mi = 0; mi < 4; mi++)
                af[mi] = *(const bf16x8*)(As + kc * 4096 + (wm * 64 + mi * 16 + ln) * 32 + qd * 8);
#pragma unroll
            for (int ni = 0; ni < 4; ni++)
                bfr[ni] = *(const bf16x8*)(Bs + kc * 4096 + (wn * 64 + ni * 16 + ln) * 32 + qd * 8);
            if (swapped) {
#pragma unroll
                for (int mi = 0; mi < 4; mi++)
#pragma unroll
                    for (int ni = 0; ni < 4; ni++)
                        acc[mi][ni] = __builtin_amdgcn_mfma_f32_16x16x32_bf16(bfr[ni], af[mi],
                                                                              acc[mi][ni], 0, 0, 0);
            } else {
#pragma unroll
                for (int mi = 0; mi < 4; mi++)
#pragma unroll
                    for (int ni = 0; ni < 4; ni++)
                        acc[mi][ni] = __builtin_amdgcn_mfma_f32_16x16x32_bf16(af[mi], bfr[ni],
                                                                              acc[mi][ni], 0, 0, 0);
            }
        }
        __syncthreads();
    }

    if (swapped) {
        // D[n][m]: lane holds x-row s (fixed), 4 consecutive W-cols (d)
        bf16* out = qkv + (size_t)z * M_TOT * D_MODEL;
#pragma unroll
        for (int mi = 0; mi < 4; mi++) {
            int srow = m0 + wm * 64 + mi * 16 + ln;
            int b = srow >> 11, s = srow & 2047;
#pragma unroll
            for (int ni = 0; ni < 4; ni++) {
                int colz = (n0 & 1023) + wn * 64 + ni * 16 + qd * 4;
                f32x4 bb = *(const f32x4*)(bias + colz);
                int h = colz >> 6, d = colz & 63;
                bf16x4 p;
#pragma unroll
                for (int r = 0; r < 4; r++)
                    p[r] = (bf16)((acc[mi][ni][r] + bb[r]) * scale);
                *(bf16x4*)(out + (((size_t)(b * NHEAD + h)) * SEQ + s) * DKH + d) = p;
            }
        }
    } else {
        // D[m][n]: lane holds W-col d (fixed), 4 consecutive x-rows (s) -> V^T direct
#pragma unroll
        for (int ni = 0; ni < 4; ni++) {
            int colz = (n0 & 1023) + wn * 64 + ni * 16 + ln;
            float bcol = bias[colz];
            int h = colz >> 6, d = colz & 63;
#pragma unroll
            for (int mi = 0; mi < 4; mi++) {
                int rb = m0 + wm * 64 + mi * 16 + qd * 4;
                int b = rb >> 11, s = rb & 2047;
                bf16x4 p;
#pragma unroll
                for (int r = 0; r < 4; r++)
                    p[r] = (bf16)(acc[mi][ni][r] + bcol);
                *(bf16x4*)(vtg + (((size_t)(b * NHEAD + h)) * DKH + d) * SEQ + s) = p;
            }
        }
    }
}

// ---------------- flash attention v4: transposed-score trick ----------------
#define PROW 40
__global__ __launch_bounds__(256, 4) void k_attn(const bf16* __restrict__ qg,
                                                 const bf16* __restrict__ kg,
                                                 const bf16* __restrict__ vtg,
                                                 bf16* __restrict__ og) {
    __shared__ bf16 Ks[2 * 64 * 32];        // 8 KB
    __shared__ bf16 Vs[2 * 64 * 32];        // 8 KB
    __shared__ bf16 Ps[4 * 2 * 32 * PROW];  // 20 KB

    int tid = threadIdx.x;
    int lane = tid & 63, wid = tid >> 6;
    int ln = lane & 15, qd = lane >> 4;
    int bh = blockIdx.y;
    int q0 = blockIdx.x * 128;
    int b = bh >> 4, h = bh & 15;

    const bf16* qp = qg + (size_t)bh * SEQ * DKH;
    const bf16* kp = kg + (size_t)bh * SEQ * DKH;
    const bf16* vp = vtg + (size_t)bh * DKH * SEQ;

    // Q fragments (pre-scaled by log2e/8), used as B operand of swapped score MFMA
    bf16x8 qa[2][2];
#pragma unroll
    for (int mi = 0; mi < 2; mi++)
#pragma unroll
        for (int kc = 0; kc < 2; kc++)
            qa[mi][kc] = *(const bf16x8*)(qp + (size_t)(q0 + wid * 32 + mi * 16 + ln) * DKH
                                          + kc * 32 + qd * 8);

    // ones B-fragment: B[k][0]=1 for all k -> lanes with ln==0 hold 1.0
    bf16 onev = (bf16)((ln == 0) ? 1.0f : 0.0f);
    bf16x8 ones_frag = {onev, onev, onev, onev, onev, onev, onev, onev};

    f32x4 zero4 = {0.f, 0.f, 0.f, 0.f};
    f32x4 o_acc[2][4];
    f32x4 l_acc[2];
#pragma unroll
    for (int mi = 0; mi < 2; mi++) {
        l_acc[mi] = zero4;
#pragma unroll
        for (int nd = 0; nd < 4; nd++) o_acc[mi][nd] = zero4;
    }

    bf16* Pw = Ps + wid * 2 * 32 * PROW;

    for (int kt = 0; kt < SEQ; kt += 64) {
        // stage K tile -> Ks[2][64][32] and Vt tile -> Vs[2][64][32] (chunked, 64B rows)
#pragma unroll
        for (int t = 0; t < 2; t++) {
            int c = t * 256 + tid;                 // 0..511, 16B each
            int ch = c >> 8, w = c & 255;
            int row = w >> 2, part = w & 3;
            async_ld16(kp + (size_t)(kt + row) * DKH + ch * 32 + part * 8,
                       Ks + (c & ~63) * 8);
            async_ld16(vp + (size_t)row * SEQ + kt + ch * 32 + part * 8,
                       Vs + (c & ~63) * 8);
        }
        __syncthreads();

        // S^T = K Q^T (log2 domain): A=K-frag, B=Q-frag; row=key qd*4+r, col=q=ln
        f32x4 sc[2][4];
#pragma unroll
        for (int mi = 0; mi < 2; mi++)
#pragma unroll
            for (int ni = 0; ni < 4; ni++) sc[mi][ni] = zero4;
#pragma unroll
        for (int kc = 0; kc < 2; kc++) {
#pragma unroll
            for (int ni = 0; ni < 4; ni++) {
                bf16x8 kb = *(const bf16x8*)(Ks + kc * 2048 + (ni * 16 + ln) * 32 + qd * 8);
#pragma unroll
                for (int mi = 0; mi < 2; mi++)
                    sc[mi][ni] = __builtin_amdgcn_mfma_f32_16x16x32_bf16(kb, qa[mi][kc],
                                                                         sc[mi][ni], 0, 0, 0);
            }
        }

        // P = exp2(S): lane owns 4 consecutive keys of P-row q=mi*16+ln -> b64 write
#pragma unroll
        for (int mi = 0; mi < 2; mi++) {
#pragma unroll
            for (int ni = 0; ni < 4; ni++) {
                bf16x4 p4;
#pragma unroll
                for (int r = 0; r < 4; r++)
                    p4[r] = (bf16)__builtin_amdgcn_exp2f(sc[mi][ni][r]);
                *(bf16x4*)(Pw + (ni >> 1) * 32 * PROW + (mi * 16 + ln) * PROW
                           + (ni & 1) * 16 + qd * 4) = p4;
            }
        }

        // O += P V ; l += P * ones  (A=P from LDS round-trip)
#pragma unroll
        for (int kc2 = 0; kc2 < 2; kc2++) {
            bf16x8 pf[2];
#pragma unroll
            for (int mi = 0; mi < 2; mi++) {
                pf[mi] = *(const bf16x8*)(Pw + kc2 * 32 * PROW + (mi * 16 + ln) * PROW + qd * 8);
                l_acc[mi] = __builtin_amdgcn_mfma_f32_16x16x32_bf16(pf[mi], ones_frag,
                                                                    l_acc[mi], 0, 0, 0);
            }
#pragma unroll
            for (int nd = 0; nd < 4; nd++) {
                bf16x8 vf = *(const bf16x8*)(Vs + kc2 * 2048 + (nd * 16 + ln) * 32 + qd * 8);
#pragma unroll
                for (int mi = 0; mi < 2; mi++)
                    o_acc[mi][nd] = __builtin_amdgcn_mfma_f32_16x16x32_bf16(pf[mi], vf,
                                                                            o_acc[mi][nd], 0, 0, 0);
            }
        }
        __syncthreads();
    }

    // normalize and store O as bf16 [B,S,H*Dk]; row-sum lives in col 0 (lanes ln==0)
#pragma unroll
    for (int mi = 0; mi < 2; mi++) {
#pragma unroll
        for (int r = 0; r < 4; r++) {
            float lsum = __shfl(l_acc[mi][r], lane & 48, 64);  // broadcast from ln==0 of this qd
            float inv = 1.0f / lsum;
            int s = q0 + wid * 32 + mi * 16 + qd * 4 + r;
            size_t rowoff = ((size_t)b * SEQ + s) * D_MODEL + h * DKH;
#pragma unroll
            for (int nd = 0; nd < 4; nd++)
                og[rowoff + nd * 16 + ln] = (bf16)(o_acc[mi][nd][r] * inv);
        }
    }
}

// ---------------- output GEMM: O[8192x1024] @ Wo + bo -> fp32 ----------------
// Same BK=64 + XCD-swizzled grid (x=m, y=n). Transposed epilogue, float4 stores.
// No min-waves bound (R6 spill lesson).
__global__ __launch_bounds__(256) void k_gemm_out(const bf16* __restrict__ ob,
                                                  const bf16* __restrict__ wot,
                                                  const float* __restrict__ bo,
                                                  float* __restrict__ out) {
    __shared__ bf16 As[2 * 128 * 32];
    __shared__ bf16 Bs[2 * 128 * 32];

    int tid = threadIdx.x;
    int lane = tid & 63, wid = tid >> 6;
    int ln = lane & 15, qd = lane >> 4;
    int wm = wid >> 1, wn = wid & 1;
    int m0 = blockIdx.x * 128, n0 = blockIdx.y * 128;

    f32x4 zero4 = {0.f, 0.f, 0.f, 0.f};
    f32x4 acc[4][4];
#pragma unroll
    for (int i = 0; i < 4; i++)
#pragma unroll
        for (int j = 0; j < 4; j++) acc[i][j] = zero4;

    for (int k0 = 0; k0 < D_MODEL; k0 += 64) {
#pragma unroll
        for (int t = 0; t < 4; t++) {
            int c = t * 256 + tid;
            int ch = c >> 9, w = c & 511;
            int row = w >> 2, part = w & 3;
            async_ld16(ob + (size_t)(m0 + row) * D_MODEL + k0 + ch * 32 + part * 8,
                       As + ch * 4096 + (w & ~63) * 8);
            async_ld16(wot + (size_t)(n0 + row) * D_MODEL + k0 + ch * 32 + part * 8,
                       Bs + ch * 4096 + (w & ~63) * 8);
        }
        __syncthreads();
#pragma unroll
        for (int kc = 0; kc < 2; kc++) {
            bf16x8 af[4], bfr[4];
#pragma unroll
            for (int mi = 0; mi < 4; mi++)
                af[mi] = *(const bf16x8*)(As + kc * 4096 + (wm * 64 + mi * 16 + ln) * 32 + qd * 8);
#pragma unroll
            for (int ni = 0; ni < 4; ni++)
                bfr[ni] = *(const bf16x8*)(Bs + kc * 4096 + (wn * 64 + ni * 16 + ln) * 32 + qd * 8);
#pragma unroll
            for (int mi = 0; mi < 4; mi++)
#pragma unroll
                for (int ni = 0; ni < 4; ni++)
                    acc[mi][ni] = __builtin_amdgcn_mfma_f32_16x16x32_bf16(bfr[ni], af[mi],
                                                                          acc[mi][ni], 0, 0, 0);
        }
        __syncthreads();
    }

#pragma unroll
    for (int mi = 0; mi < 4; mi++) {
        int row = m0 + wm * 64 + mi * 16 + ln;
#pragma unroll
        for (int ni = 0; ni < 4; ni++) {
            int col4 = n0 + wn * 64 + ni * 16 + qd * 4;
            f32x4 bb = *(const f32x4*)(bo + col4);
            f32x4 v;
#pragma unroll
            for (int r = 0; r < 4; r++) v[r] = acc[mi][ni][r] + bb[r];
            *(f32x4*)(out + (size_t)row * D_MODEL + col4) = v;
        }
    }
}

extern "C" void kernel_launch(void* const* d_in, const int* in_sizes, int n_in,
                              void* d_out, int out_size, void* d_ws, size_t ws_size,
                              hipStream_t stream) {
    const float* x  = (const float*)d_in[0];
    const float* wq = (const float*)d_in[1];
    const float* bq = (const float*)d_in[2];
    const float* wk = (const float*)d_in[3];
    const float* bk = (const float*)d_in[4];
    const float* wv = (const float*)d_in[5];
    const float* bv = (const float*)d_in[6];
    const float* wo = (const float*)d_in[7];
    const float* bo = (const float*)d_in[8];
    float* out = (float*)d_out;

    char* ws = (char*)d_ws;
    bf16* xb  = (bf16*)ws;                    // 16.8 MB (reused as og after QKV GEMM)
    bf16* wt  = (bf16*)(ws + 16777216);       //  8.4 MB (wq,wk,wv,wo transposed, contiguous)
    bf16* qkv = (bf16*)(ws + 25165824);       // Q,K
    bf16* vtg = (bf16*)(ws + 75497472);       // V^T written directly by GEMM
    bf16* og  = xb;

    k_cvt<<<dim3(8192 + 4096), dim3(256), 0, stream>>>(x, xb, wq, wk, wv, wo, wt);
    k_gemm_qkv<<<dim3(64, 24), dim3(256), 0, stream>>>(xb, wt, bq, bk, bv, qkv, vtg);
    k_attn<<<dim3(16, 64), dim3(256), 0, stream>>>(qkv, qkv + (size_t)M_TOT * D_MODEL, vtg, og);
    k_gemm_out<<<dim3(64, 8), dim3(256), 0, stream>>>(og, wt + 3 * (size_t)D_MODEL * D_MODEL,
                                                      bo, out);
}

// Round 8
// 276.403 us; speedup vs baseline: 2.4797x; 1.0138x over previous
//
#include <hip/hip_runtime.h>
#include <hip/hip_bf16.h>
#include <cstdint>

#define D_MODEL 1024
#define NHEAD 16
#define DKH 64
#define BATCH 4
#define SEQ 2048
#define M_TOT (BATCH*SEQ)   // 8192

typedef __bf16 bf16;
typedef __bf16 bf16x8 __attribute__((ext_vector_type(8)));
typedef __bf16 bf16x4 __attribute__((ext_vector_type(4)));
typedef float  f32x4  __attribute__((ext_vector_type(4)));

// async global->LDS, 16B per lane. LDS dest must be wave-uniform base; HW adds lane*16.
__device__ __forceinline__ void async_ld16(const void* g, void* l) {
    __builtin_amdgcn_global_load_lds(
        (__attribute__((address_space(1))) void*)(uintptr_t)g,
        (__attribute__((address_space(3))) void*)(uintptr_t)l,
        16, 0, 0);
}

// ---------------- merged convert: x fp32->bf16 (blocks 0..8191) and
// weight convert+transpose W[K][N] fp32 -> Wt[N][K] bf16 (blocks 8192..12287) ----------------
__global__ __launch_bounds__(256) void k_cvt(const float* __restrict__ x,
                                             bf16* __restrict__ xb,
                                             const float* __restrict__ wq,
                                             const float* __restrict__ wk,
                                             const float* __restrict__ wv,
                                             const float* __restrict__ wo,
                                             bf16* __restrict__ wt) {
    __shared__ float t[32][33];
    int bid = blockIdx.x;
    if (bid < 8192) {
        int i = (bid * 256 + threadIdx.x) * 4;
        float4 f = *(const float4*)(x + i);
        bf16x4 o;
        o[0] = (bf16)f.x; o[1] = (bf16)f.y; o[2] = (bf16)f.z; o[3] = (bf16)f.w;
        *(bf16x4*)(xb + i) = o;
    } else {
        int wb = bid - 8192;                  // 0..4095
        int z = wb >> 10;
        int rem = wb & 1023;
        const float* W = (z == 0) ? wq : (z == 1) ? wk : (z == 2) ? wv : wo;
        bf16* T = wt + (size_t)z * D_MODEL * D_MODEL;
        int tx = threadIdx.x & 31, ty = threadIdx.x >> 5;   // (32,8)
        int bx = (rem & 31) * 32, by = (rem >> 5) * 32;
#pragma unroll
        for (int i = 0; i < 4; i++)
            t[ty + i * 8][tx] = W[(size_t)(by + ty + i * 8) * D_MODEL + bx + tx];
        __syncthreads();
#pragma unroll
        for (int i = 0; i < 4; i++)
            T[(size_t)(bx + ty + i * 8) * D_MODEL + by + tx] = (bf16)t[tx][ty + i * 8];
    }
}

// ---------------- fused QKV GEMM, z-merged + XCD-swizzled + BK=64 ----------------
// Grid (64 m-tiles, 24 n-tiles over 3072 cols). id = bx + 64*by -> id%8 = bx%8:
// all n-tiles of one m-tile run on the SAME XCD -> A-tile HBM-fetched once.
// NOTE R6 lesson: NO min-waves launch bound — forcing 4 waves/SIMD on a
// ~120-VGPR kernel spilled acc to scratch (WRITE_SIZE 49MB->1.4GB, 5x slower).
__global__ __launch_bounds__(256) void k_gemm_qkv(const bf16* __restrict__ xb,
                                                  const bf16* __restrict__ wt,
                                                  const float* __restrict__ bq,
                                                  const float* __restrict__ bk,
                                                  const float* __restrict__ bv,
                                                  bf16* __restrict__ qkv,
                                                  bf16* __restrict__ vtg) {
    __shared__ bf16 As[2 * 128 * 32];   // 16 KB: two 32-wide k-panels
    __shared__ bf16 Bs[2 * 128 * 32];   // 16 KB

    int tid = threadIdx.x;
    int lane = tid & 63, wid = tid >> 6;
    int ln = lane & 15, qd = lane >> 4;
    int wm = wid >> 1, wn = wid & 1;
    int m0 = blockIdx.x * 128;                 // m-tile (x-fastest -> XCD pin)
    int n0 = blockIdx.y * 128;                 // global col in [0,3072)
    int z = n0 >> 10;
    const float* bias = (z == 0) ? bq : (z == 1) ? bk : bv;
    float scale = (z == 0) ? 0.125f * 1.44269504088896f : 1.0f;  // 1/sqrt(Dk)*log2e folded into Q
    bool swapped = (z < 2);

    f32x4 zero4 = {0.f, 0.f, 0.f, 0.f};
    f32x4 acc[4][4];
#pragma unroll
    for (int i = 0; i < 4; i++)
#pragma unroll
        for (int j = 0; j < 4; j++) acc[i][j] = zero4;

    for (int k0 = 0; k0 < D_MODEL; k0 += 64) {
#pragma unroll
        for (int t = 0; t < 4; t++) {
            int c = t * 256 + tid;             // 0..1023, 16B each
            int ch = c >> 9, w = c & 511;      // panel, slot
            int row = w >> 2, part = w & 3;
            async_ld16(xb + (size_t)(m0 + row) * D_MODEL + k0 + ch * 32 + part * 8,
                       As + ch * 4096 + (w & ~63) * 8);
            async_ld16(wt + (size_t)(n0 + row) * D_MODEL + k0 + ch * 32 + part * 8,
                       Bs + ch * 4096 + (w & ~63) * 8);
        }
        __syncthreads();
#pragma unroll
        for (int kc = 0; kc < 2; kc++) {
            bf16x8 af[4], bfr[4];
#pragma unroll
            for (int mi = 0; mi < 4; mi++)
                af[mi] = *(const bf16x8*)(As + kc * 4096 + (wm * 64 + mi * 16 + ln) * 32 + qd * 8);
#pragma unroll
            for (int ni = 0; ni < 4; ni++)
                bfr[ni] = *(const bf16x8*)(Bs + kc * 4096 + (wn * 64 + ni * 16 + ln) * 32 + qd * 8);
            if (swapped) {
#pragma unroll
                for (int mi = 0; mi < 4; mi++)
#pragma unroll
                    for (int ni = 0; ni < 4; ni++)
                        acc[mi][ni] = __builtin_amdgcn_mfma_f32_16x16x32_bf16(bfr[ni], af[mi],
                                                                              acc[mi][ni], 0, 0, 0);
            } else {
#pragma unroll
                for (int mi = 0; mi < 4; mi++)
#pragma unroll
                    for (int ni = 0; ni < 4; ni++)
                        acc[mi][ni] = __builtin_amdgcn_mfma_f32_16x16x32_bf16(af[mi], bfr[ni],
                                                                              acc[mi][ni], 0, 0, 0);
            }
        }
        __syncthreads();
    }

    if (swapped) {
        // D[n][m]: lane holds x-row s (fixed), 4 consecutive W-cols (d)
        bf16* out = qkv + (size_t)z * M_TOT * D_MODEL;
#pragma unroll
        for (int mi = 0; mi < 4; mi++) {
            int srow = m0 + wm * 64 + mi * 16 + ln;
            int b = srow >> 11, s = srow & 2047;
#pragma unroll
            for (int ni = 0; ni < 4; ni++) {
                int colz = (n0 & 1023) + wn * 64 + ni * 16 + qd * 4;
                f32x4 bb = *(const f32x4*)(bias + colz);
                int h = colz >> 6, d = colz & 63;
                bf16x4 p;
#pragma unroll
                for (int r = 0; r < 4; r++)
                    p[r] = (bf16)((acc[mi][ni][r] + bb[r]) * scale);
                *(bf16x4*)(out + (((size_t)(b * NHEAD + h)) * SEQ + s) * DKH + d) = p;
            }
        }
    } else {
        // D[m][n]: lane holds W-col d (fixed), 4 consecutive x-rows (s) -> V^T direct
#pragma unroll
        for (int ni = 0; ni < 4; ni++) {
            int colz = (n0 & 1023) + wn * 64 + ni * 16 + ln;
            float bcol = bias[colz];
            int h = colz >> 6, d = colz & 63;
#pragma unroll
            for (int mi = 0; mi < 4; mi++) {
                int rb = m0 + wm * 64 + mi * 16 + qd * 4;
                int b = rb >> 11, s = rb & 2047;
                bf16x4 p;
#pragma unroll
                for (int r = 0; r < 4; r++)
                    p[r] = (bf16)(acc[mi][ni][r] + bcol);
                *(bf16x4*)(vtg + (((size_t)(b * NHEAD + h)) * DKH + d) * SEQ + s) = p;
            }
        }
    }
}

// ---------------- flash attention v5 ----------------
// R8: (1) grid swapped to (64 bh, 16 q-tiles): id%8 = bh%8 -> all 16 q-blocks
// of one head share an XCD; K/V HBM-fetched once, re-reads are L2 hits ->
// shorter pre-barrier vmcnt drain. (2) PROW 40->36 (18 words: ln*18 mod 32
// hits all 16 residues -> no ln/ln+8 bank alias on Ps). pf reads = 2x b64.
#define PROW 36
__global__ __launch_bounds__(256, 4) void k_attn(const bf16* __restrict__ qg,
                                                 const bf16* __restrict__ kg,
                                                 const bf16* __restrict__ vtg,
                                                 bf16* __restrict__ og) {
    __shared__ bf16 Ks[2 * 64 * 32];        // 8 KB
    __shared__ bf16 Vs[2 * 64 * 32];        // 8 KB
    __shared__ bf16 Ps[4 * 2 * 32 * PROW];  // 18 KB

    int tid = threadIdx.x;
    int lane = tid & 63, wid = tid >> 6;
    int ln = lane & 15, qd = lane >> 4;
    int bh = blockIdx.x;                    // x-fastest -> XCD pin per head
    int q0 = blockIdx.y * 128;
    int b = bh >> 4, h = bh & 15;

    const bf16* qp = qg + (size_t)bh * SEQ * DKH;
    const bf16* kp = kg + (size_t)bh * SEQ * DKH;
    const bf16* vp = vtg + (size_t)bh * DKH * SEQ;

    // Q fragments (pre-scaled by log2e/8), used as B operand of swapped score MFMA
    bf16x8 qa[2][2];
#pragma unroll
    for (int mi = 0; mi < 2; mi++)
#pragma unroll
        for (int kc = 0; kc < 2; kc++)
            qa[mi][kc] = *(const bf16x8*)(qp + (size_t)(q0 + wid * 32 + mi * 16 + ln) * DKH
                                          + kc * 32 + qd * 8);

    // ones B-fragment: B[k][0]=1 for all k -> lanes with ln==0 hold 1.0
    bf16 onev = (bf16)((ln == 0) ? 1.0f : 0.0f);
    bf16x8 ones_frag = {onev, onev, onev, onev, onev, onev, onev, onev};

    f32x4 zero4 = {0.f, 0.f, 0.f, 0.f};
    f32x4 o_acc[2][4];
    f32x4 l_acc[2];
#pragma unroll
    for (int mi = 0; mi < 2; mi++) {
        l_acc[mi] = zero4;
#pragma unroll
        for (int nd = 0; nd < 4; nd++) o_acc[mi][nd] = zero4;
    }

    bf16* Pw = Ps + wid * 2 * 32 * PROW;

    for (int kt = 0; kt < SEQ; kt += 64) {
        // stage K tile -> Ks[2][64][32] and Vt tile -> Vs[2][64][32] (chunked, 64B rows)
#pragma unroll
        for (int t = 0; t < 2; t++) {
            int c = t * 256 + tid;                 // 0..511, 16B each
            int ch = c >> 8, w = c & 255;
            int row = w >> 2, part = w & 3;
            async_ld16(kp + (size_t)(kt + row) * DKH + ch * 32 + part * 8,
                       Ks + (c & ~63) * 8);
            async_ld16(vp + (size_t)row * SEQ + kt + ch * 32 + part * 8,
                       Vs + (c & ~63) * 8);
        }
        __syncthreads();

        // S^T = K Q^T (log2 domain): A=K-frag, B=Q-frag; row=key qd*4+r, col=q=ln
        f32x4 sc[2][4];
#pragma unroll
        for (int mi = 0; mi < 2; mi++)
#pragma unroll
            for (int ni = 0; ni < 4; ni++) sc[mi][ni] = zero4;
#pragma unroll
        for (int kc = 0; kc < 2; kc++) {
#pragma unroll
            for (int ni = 0; ni < 4; ni++) {
                bf16x8 kb = *(const bf16x8*)(Ks + kc * 2048 + (ni * 16 + ln) * 32 + qd * 8);
#pragma unroll
                for (int mi = 0; mi < 2; mi++)
                    sc[mi][ni] = __builtin_amdgcn_mfma_f32_16x16x32_bf16(kb, qa[mi][kc],
                                                                         sc[mi][ni], 0, 0, 0);
            }
        }

        // P = exp2(S): lane owns 4 consecutive keys of P-row q=mi*16+ln -> b64 write
#pragma unroll
        for (int mi = 0; mi < 2; mi++) {
#pragma unroll
            for (int ni = 0; ni < 4; ni++) {
                bf16x4 p4;
#pragma unroll
                for (int r = 0; r < 4; r++)
                    p4[r] = (bf16)__builtin_amdgcn_exp2f(sc[mi][ni][r]);
                *(bf16x4*)(Pw + (ni >> 1) * 32 * PROW + (mi * 16 + ln) * PROW
                           + (ni & 1) * 16 + qd * 4) = p4;
            }
        }

        // O += P V ; l += P * ones  (A=P from LDS round-trip; 2x b64 reads, 72B rows)
#pragma unroll
        for (int kc2 = 0; kc2 < 2; kc2++) {
            bf16x8 pf[2];
#pragma unroll
            for (int mi = 0; mi < 2; mi++) {
                const bf16* pr = Pw + kc2 * 32 * PROW + (mi * 16 + ln) * PROW + qd * 8;
                bf16x4 lo = *(const bf16x4*)(pr);
                bf16x4 hi = *(const bf16x4*)(pr + 4);
                pf[mi][0] = lo[0]; pf[mi][1] = lo[1]; pf[mi][2] = lo[2]; pf[mi][3] = lo[3];
                pf[mi][4] = hi[0]; pf[mi][5] = hi[1]; pf[mi][6] = hi[2]; pf[mi][7] = hi[3];
                l_acc[mi] = __builtin_amdgcn_mfma_f32_16x16x32_bf16(pf[mi], ones_frag,
                                                                    l_acc[mi], 0, 0, 0);
            }
#pragma unroll
            for (int nd = 0; nd < 4; nd++) {
                bf16x8 vf = *(const bf16x8*)(Vs + kc2 * 2048 + (nd * 16 + ln) * 32 + qd * 8);
#pragma unroll
                for (int mi = 0; mi < 2; mi++)
                    o_acc[mi][nd] = __builtin_amdgcn_mfma_f32_16x16x32_bf16(pf[mi], vf,
                                                                            o_acc[mi][nd], 0, 0, 0);
            }
        }
        __syncthreads();
    }

    // normalize and store O as bf16 [B,S,H*Dk]; row-sum lives in col 0 (lanes ln==0)
#pragma unroll
    for (int mi = 0; mi < 2; mi++) {
#pragma unroll
        for (int r = 0; r < 4; r++) {
            float lsum = __shfl(l_acc[mi][r], lane & 48, 64);  // broadcast from ln==0 of this qd
            float inv = 1.0f / lsum;
            int s = q0 + wid * 32 + mi * 16 + qd * 4 + r;
            size_t rowoff = ((size_t)b * SEQ + s) * D_MODEL + h * DKH;
#pragma unroll
            for (int nd = 0; nd < 4; nd++)
                og[rowoff + nd * 16 + ln] = (bf16)(o_acc[mi][nd][r] * inv);
        }
    }
}

// ---------------- output GEMM: O[8192x1024] @ Wo + bo -> fp32 ----------------
// BK=64 + XCD-swizzled grid (x=m, y=n). Transposed epilogue, float4 stores.
__global__ __launch_bounds__(256) void k_gemm_out(const bf16* __restrict__ ob,
                                                  const bf16* __restrict__ wot,
                                                  const float* __restrict__ bo,
                                                  float* __restrict__ out) {
    __shared__ bf16 As[2 * 128 * 32];
    __shared__ bf16 Bs[2 * 128 * 32];

    int tid = threadIdx.x;
    int lane = tid & 63, wid = tid >> 6;
    int ln = lane & 15, qd = lane >> 4;
    int wm = wid >> 1, wn = wid & 1;
    int m0 = blockIdx.x * 128, n0 = blockIdx.y * 128;

    f32x4 zero4 = {0.f, 0.f, 0.f, 0.f};
    f32x4 acc[4][4];
#pragma unroll
    for (int i = 0; i < 4; i++)
#pragma unroll
        for (int j = 0; j < 4; j++) acc[i][j] = zero4;

    for (int k0 = 0; k0 < D_MODEL; k0 += 64) {
#pragma unroll
        for (int t = 0; t < 4; t++) {
            int c = t * 256 + tid;
            int ch = c >> 9, w = c & 511;
            int row = w >> 2, part = w & 3;
            async_ld16(ob + (size_t)(m0 + row) * D_MODEL + k0 + ch * 32 + part * 8,
                       As + ch * 4096 + (w & ~63) * 8);
            async_ld16(wot + (size_t)(n0 + row) * D_MODEL + k0 + ch * 32 + part * 8,
                       Bs + ch * 4096 + (w & ~63) * 8);
        }
        __syncthreads();
#pragma unroll
        for (int kc = 0; kc < 2; kc++) {
            bf16x8 af[4], bfr[4];
#pragma unroll
            for (int mi = 0; mi < 4; mi++)
                af[mi] = *(const bf16x8*)(As + kc * 4096 + (wm * 64 + mi * 16 + ln) * 32 + qd * 8);
#pragma unroll
            for (int ni = 0; ni < 4; ni++)
                bfr[ni] = *(const bf16x8*)(Bs + kc * 4096 + (wn * 64 + ni * 16 + ln) * 32 + qd * 8);
#pragma unroll
            for (int mi = 0; mi < 4; mi++)
#pragma unroll
                for (int ni = 0; ni < 4; ni++)
                    acc[mi][ni] = __builtin_amdgcn_mfma_f32_16x16x32_bf16(bfr[ni], af[mi],
                                                                          acc[mi][ni], 0, 0, 0);
        }
        __syncthreads();
    }

#pragma unroll
    for (int mi = 0; mi < 4; mi++) {
        int row = m0 + wm * 64 + mi * 16 + ln;
#pragma unroll
        for (int ni = 0; ni < 4; ni++) {
            int col4 = n0 + wn * 64 + ni * 16 + qd * 4;
            f32x4 bb = *(const f32x4*)(bo + col4);
            f32x4 v;
#pragma unroll
            for (int r = 0; r < 4; r++) v[r] = acc[mi][ni][r] + bb[r];
            *(f32x4*)(out + (size_t)row * D_MODEL + col4) = v;
        }
    }
}

extern "C" void kernel_launch(void* const* d_in, const int* in_sizes, int n_in,
                              void* d_out, int out_size, void* d_ws, size_t ws_size,
                              hipStream_t stream) {
    const float* x  = (const float*)d_in[0];
    const float* wq = (const float*)d_in[1];
    const float* bq = (const float*)d_in[2];
    const float* wk = (const float*)d_in[3];
    const float* bk = (const float*)d_in[4];
    const float* wv = (const float*)d_in[5];
    const float* bv = (const float*)d_in[6];
    const float* wo = (const float*)d_in[7];
    const float* bo = (const float*)d_in[8];
    float* out = (float*)d_out;

    char* ws = (char*)d_ws;
    bf16* xb  = (bf16*)ws;                    // 16.8 MB (reused as og after QKV GEMM)
    bf16* wt  = (bf16*)(ws + 16777216);       //  8.4 MB (wq,wk,wv,wo transposed, contiguous)
    bf16* qkv = (bf16*)(ws + 25165824);       // Q,K
    bf16* vtg = (bf16*)(ws + 75497472);       // V^T written directly by GEMM
    bf16* og  = xb;

    k_cvt<<<dim3(8192 + 4096), dim3(256), 0, stream>>>(x, xb, wq, wk, wv, wo, wt);
    k_gemm_qkv<<<dim3(64, 24), dim3(256), 0, stream>>>(xb, wt, bq, bk, bv, qkv, vtg);
    k_attn<<<dim3(64, 16), dim3(256), 0, stream>>>(qkv, qkv + (size_t)M_TOT * D_MODEL, vtg, og);
    k_gemm_out<<<dim3(64, 8), dim3(256), 0, stream>>>(og, wt + 3 * (size_t)D_MODEL * D_MODEL,
                                                      bo, out);
}